// Round 5
// baseline (294.247 us; speedup 1.0000x reference)
//
#include <hip/hip_runtime.h>

#define T_TOK 1024
#define H_DIM 1024
#define I_DIM 768
#define E_NUM 8

// prep ranges (in 8-element groups)
#define G13 1572864   // 8*1536*1024/8
#define G2   786432   // 8*1024*768/8
#define GX   131072   // 1024*1024/8

typedef __bf16 bf16x8 __attribute__((ext_vector_type(8)));
typedef float  f32x4  __attribute__((ext_vector_type(4)));

__device__ inline bf16x8 cvt8(float4 a, float4 b, float s) {
    bf16x8 o;
    o[0] = (__bf16)(a.x * s); o[1] = (__bf16)(a.y * s);
    o[2] = (__bf16)(a.z * s); o[3] = (__bf16)(a.w * s);
    o[4] = (__bf16)(b.x * s); o[5] = (__bf16)(b.y * s);
    o[6] = (__bf16)(b.z * s); o[7] = (__bf16)(b.w * s);
    return o;
}

// ---- prep: dequant w13/w2 -> bf16, convert x -> bf16, zero out -----------
__global__ __launch_bounds__(256) void prep_kernel(
    const float* __restrict__ w13, const float* __restrict__ w13s,
    const float* __restrict__ w2,  const float* __restrict__ w2s,
    const float* __restrict__ x,   float4* __restrict__ out4,
    __bf16* __restrict__ w13d, __bf16* __restrict__ w2d, __bf16* __restrict__ xbf)
{
    int g = blockIdx.x * 256 + threadIdx.x;
    if (g < G13) {
        int k8 = g & 127;               // 128 groups per 1024-k row
        int row = g >> 7;               // e*1536 + n
        float s = w13s[(row << 3) | (k8 >> 4)];
        const float4* src = (const float4*)w13 + (size_t)g * 2;
        *(bf16x8*)(w13d + (size_t)g * 8) = cvt8(src[0], src[1], s);
    } else if (g < G13 + G2) {
        int g2 = g - G13;
        unsigned row = (unsigned)g2 / 96u;   // e*1024 + h (96 groups per 768-k row)
        int k8 = g2 - row * 96;
        float s = w2s[row * 6 + (k8 >> 4)];
        const float4* src = (const float4*)w2 + (size_t)g2 * 2;
        *(bf16x8*)(w2d + (size_t)g2 * 8) = cvt8(src[0], src[1], s);
    } else if (g < G13 + G2 + GX) {
        int gx = g - (G13 + G2);
        const float4* src = (const float4*)x + (size_t)gx * 2;
        *(bf16x8*)(xbf + (size_t)gx * 8) = cvt8(src[0], src[1], 1.0f);
    } else {
        int go = g - (G13 + G2 + GX);
        float4 z = make_float4(0.f, 0.f, 0.f, 0.f);
        out4[2 * go] = z; out4[2 * go + 1] = z;
    }
}

// ---- router: single block, LDS counters + scan ---------------------------
__global__ __launch_bounds__(1024) void router_kernel(
    const float* __restrict__ logits,
    int* __restrict__ counts, int* __restrict__ base,
    int* __restrict__ tok_list, float* __restrict__ wt_list)
{
    __shared__ int cnt[E_NUM];
    const int t = threadIdx.x;
    if (t < E_NUM) cnt[t] = 0;
    __syncthreads();
    float l[E_NUM];
#pragma unroll
    for (int e = 0; e < E_NUM; e++) l[e] = logits[t * E_NUM + e];
    int e0 = 0; float m0 = l[0];
#pragma unroll
    for (int e = 1; e < E_NUM; e++) if (l[e] > m0) { m0 = l[e]; e0 = e; }
    int e1 = -1; float m1 = -3e38f;
#pragma unroll
    for (int e = 0; e < E_NUM; e++) if (e != e0 && l[e] > m1) { m1 = l[e]; e1 = e; }
    float w0 = 1.0f / (1.0f + expf(m1 - m0));
    float w1 = 1.0f - w0;
    int p0 = atomicAdd(&cnt[e0], 1);
    tok_list[e0 * T_TOK + p0] = t;
    wt_list[e0 * T_TOK + p0] = w0;
    int p1 = atomicAdd(&cnt[e1], 1);
    tok_list[e1 * T_TOK + p1] = t;
    wt_list[e1 * T_TOK + p1] = w1;
    __syncthreads();
    if (t == 0) {
        int s = 0;
        for (int e = 0; e < E_NUM; e++) { base[e] = s; counts[e] = cnt[e]; s += cnt[e]; }
    }
}

#define MFMA(A, B, C) __builtin_amdgcn_mfma_f32_16x16x32_bf16(A, B, C, 0, 0, 0)

// ---- GEMM1: gate_up = x_g @ w13d^T, + SiLU -------------------------------
// M=32 x N=128(64 gate+64 up), BK=64, VGPR-staged 2-deep pipeline + LDS dbuf
__global__ __launch_bounds__(256, 4) void gemm1_kernel(
    const __bf16* __restrict__ xbf,
    const __bf16* __restrict__ w13d,
    const int* __restrict__ counts,
    const int* __restrict__ base,
    const int* __restrict__ tok_list,
    __bf16* __restrict__ act)
{
    const int e = blockIdx.z;
    const int count = counts[e];
    const int m0 = blockIdx.y * 32;
    if (m0 >= count) return;
    const int n0 = blockIdx.x * 64;
    const int abase = base[e];

    __shared__ union {
        struct { __bf16 Bs[2][128 * 64]; __bf16 As[2][32 * 64]; } s;  // 40960 B
        float gu[32 * 132];
        int tok[32];
    } u;

    const int tid = threadIdx.x;
    if (tid < 32) {
        int r = m0 + tid;
        u.tok[tid] = (r < count) ? tok_list[e * T_TOK + r] : tok_list[e * T_TOK];
    }
    __syncthreads();

    // staging: A granule per thread (row 0..31, 8 granules/row)
    const int arow = tid >> 3, ag = tid & 7;
    const __bf16* pA = xbf + (size_t)u.tok[arow] * H_DIM + ag * 8;
    const int awo = arow * 128 + ((ag ^ (arow & 7)) << 4);
    // staging: 4 B granules per thread (row 0..127)
    const int brow = tid >> 1, bg0 = (tid & 1) * 4;
    const int nB = (brow < 64) ? (n0 + brow) : (I_DIM + n0 + brow - 64);
    const __bf16* pB = w13d + ((size_t)e * 2 * I_DIM + nB) * H_DIM + bg0 * 8;
    int bwo[4];
#pragma unroll
    for (int i = 0; i < 4; i++)
        bwo[i] = brow * 128 + (((bg0 + i) ^ (brow & 7)) << 4);

    const int wid = tid >> 6, lane = tid & 63, lrow = lane & 15, quad = lane >> 4;
    int aoff[2][2], boff[2][2];
#pragma unroll
    for (int kk = 0; kk < 2; kk++) {
        int gph = ((kk * 4 + quad) ^ (lrow & 7)) << 4;
#pragma unroll
        for (int i = 0; i < 2; i++) {
            aoff[kk][i] = (i * 16 + lrow) * 128 + gph;
            boff[kk][i] = (wid * 32 + i * 16 + lrow) * 128 + gph;
        }
    }

    f32x4 acc[2][2];
#pragma unroll
    for (int i = 0; i < 2; i++)
#pragma unroll
        for (int j = 0; j < 2; j++) { f32x4 z = {0.f, 0.f, 0.f, 0.f}; acc[i][j] = z; }

    // 2-deep register pipeline: loads survive barriers; ds_write waits precisely
    uint4 rA[2], rB[2][4];
#pragma unroll
    for (int s = 0; s < 2; s++) {
        rA[s] = *(const uint4*)(pA + s * 64);
#pragma unroll
        for (int i = 0; i < 4; i++)
            rB[s][i] = *(const uint4*)(pB + s * 64 + i * 8);
    }

#pragma unroll 2
    for (int it = 0; it < 16; ++it) {
        const int b = it & 1;
        __syncthreads();                       // all reads of buf b (2 iters ago) done
        *(uint4*)((char*)u.s.As[b] + awo) = rA[b];
#pragma unroll
        for (int i = 0; i < 4; i++)
            *(uint4*)((char*)u.s.Bs[b] + bwo[i]) = rB[b][i];
        if (it + 2 < 16) {
            const int k = (it + 2) * 64;
            rA[b] = *(const uint4*)(pA + k);
#pragma unroll
            for (int i = 0; i < 4; i++)
                rB[b][i] = *(const uint4*)(pB + k + i * 8);
        }
        __syncthreads();                       // buf b visible
        const char* Ab = (const char*)u.s.As[b];
        const char* Bb = (const char*)u.s.Bs[b];
#pragma unroll
        for (int kk = 0; kk < 2; kk++) {
            bf16x8 a0 = *(const bf16x8*)(Ab + aoff[kk][0]);
            bf16x8 a1 = *(const bf16x8*)(Ab + aoff[kk][1]);
            bf16x8 b0 = *(const bf16x8*)(Bb + boff[kk][0]);
            bf16x8 b1 = *(const bf16x8*)(Bb + boff[kk][1]);
            acc[0][0] = MFMA(a0, b0, acc[0][0]);
            acc[1][0] = MFMA(a1, b0, acc[1][0]);
            acc[0][1] = MFMA(a0, b1, acc[0][1]);
            acc[1][1] = MFMA(a1, b1, acc[1][1]);
        }
    }

    __syncthreads();   // staging dead; reuse union as gu
#pragma unroll
    for (int i = 0; i < 2; i++)
#pragma unroll
        for (int j = 0; j < 2; j++)
#pragma unroll
            for (int r = 0; r < 4; r++) {
                int m = i * 16 + quad * 4 + r;
                int c = wid * 32 + j * 16 + lrow;
                u.gu[m * 132 + c] = acc[i][j][r];
            }
    __syncthreads();

#pragma unroll
    for (int ii = 0; ii < 8; ii++) {
        int o = ii * 256 + tid;
        int m = o >> 6, c = o & 63;
        if (m0 + m < count) {
            float g  = u.gu[m * 132 + c];
            float up = u.gu[m * 132 + 64 + c];
            float a  = g / (1.0f + expf(-g)) * up;
            act[(size_t)(abase + m0 + m) * I_DIM + n0 + c] = (__bf16)a;
        }
    }
}

// ---- GEMM2: out += w * (act @ w2d^T) -------------------------------------
// M=32 x N=128, BK=64, VGPR-staged 2-deep pipeline + LDS dbuf
__global__ __launch_bounds__(256, 4) void gemm2_kernel(
    const __bf16* __restrict__ act,
    const __bf16* __restrict__ w2d,
    const int* __restrict__ counts,
    const int* __restrict__ base,
    const int* __restrict__ tok_list,
    const float* __restrict__ wt_list,
    float* __restrict__ out)
{
    const int e = blockIdx.z;
    const int count = counts[e];
    const int m0 = blockIdx.y * 32;
    if (m0 >= count) return;
    const int n0 = blockIdx.x * 128;
    const int abase = base[e];

    __shared__ struct { __bf16 Bs[2][128 * 64]; __bf16 As[2][32 * 64]; } s;  // 40960 B

    const int tid = threadIdx.x;

    const int arow = tid >> 3, ag = tid & 7;
    int gr = abase + m0 + arow;
    if (gr > 2 * T_TOK - 1) gr = 2 * T_TOK - 1;
    const __bf16* pA = act + (size_t)gr * I_DIM + ag * 8;
    const int awo = arow * 128 + ((ag ^ (arow & 7)) << 4);

    const int brow = tid >> 1, bg0 = (tid & 1) * 4;
    const __bf16* pB = w2d + ((size_t)e * H_DIM + n0 + brow) * I_DIM + bg0 * 8;
    int bwo[4];
#pragma unroll
    for (int i = 0; i < 4; i++)
        bwo[i] = brow * 128 + (((bg0 + i) ^ (brow & 7)) << 4);

    const int wid = tid >> 6, lane = tid & 63, lrow = lane & 15, quad = lane >> 4;
    int aoff[2][2], boff[2][2];
#pragma unroll
    for (int kk = 0; kk < 2; kk++) {
        int gph = ((kk * 4 + quad) ^ (lrow & 7)) << 4;
#pragma unroll
        for (int i = 0; i < 2; i++) {
            aoff[kk][i] = (i * 16 + lrow) * 128 + gph;
            boff[kk][i] = (wid * 32 + i * 16 + lrow) * 128 + gph;
        }
    }

    f32x4 acc[2][2];
#pragma unroll
    for (int i = 0; i < 2; i++)
#pragma unroll
        for (int j = 0; j < 2; j++) { f32x4 z = {0.f, 0.f, 0.f, 0.f}; acc[i][j] = z; }

    uint4 rA[2], rB[2][4];
#pragma unroll
    for (int sdeep = 0; sdeep < 2; sdeep++) {
        rA[sdeep] = *(const uint4*)(pA + sdeep * 64);
#pragma unroll
        for (int i = 0; i < 4; i++)
            rB[sdeep][i] = *(const uint4*)(pB + sdeep * 64 + i * 8);
    }

#pragma unroll 2
    for (int it = 0; it < 12; ++it) {          // K = 768
        const int b = it & 1;
        __syncthreads();
        *(uint4*)((char*)s.As[b] + awo) = rA[b];
#pragma unroll
        for (int i = 0; i < 4; i++)
            *(uint4*)((char*)s.Bs[b] + bwo[i]) = rB[b][i];
        if (it + 2 < 12) {
            const int k = (it + 2) * 64;
            rA[b] = *(const uint4*)(pA + k);
#pragma unroll
            for (int i = 0; i < 4; i++)
                rB[b][i] = *(const uint4*)(pB + k + i * 8);
        }
        __syncthreads();
        const char* Ab = (const char*)s.As[b];
        const char* Bb = (const char*)s.Bs[b];
#pragma unroll
        for (int kk = 0; kk < 2; kk++) {
            bf16x8 a0 = *(const bf16x8*)(Ab + aoff[kk][0]);
            bf16x8 a1 = *(const bf16x8*)(Ab + aoff[kk][1]);
            bf16x8 b0 = *(const bf16x8*)(Bb + boff[kk][0]);
            bf16x8 b1 = *(const bf16x8*)(Bb + boff[kk][1]);
            acc[0][0] = MFMA(a0, b0, acc[0][0]);
            acc[1][0] = MFMA(a1, b0, acc[1][0]);
            acc[0][1] = MFMA(a0, b1, acc[0][1]);
            acc[1][1] = MFMA(a1, b1, acc[1][1]);
        }
    }

    // weighted atomic scatter (tok/wt via broadcast-coalesced global loads)
#pragma unroll
    for (int i = 0; i < 2; i++)
#pragma unroll
        for (int r = 0; r < 4; r++) {
            int m = i * 16 + quad * 4 + r;
            if (m0 + m < count) {
                int   t = tok_list[e * T_TOK + m0 + m];
                float w = wt_list[e * T_TOK + m0 + m];
#pragma unroll
                for (int j = 0; j < 2; j++) {
                    int h = n0 + wid * 32 + j * 16 + lrow;
                    atomicAdd(&out[(size_t)t * H_DIM + h], w * acc[i][j][r]);
                }
            }
        }
}

extern "C" void kernel_launch(void* const* d_in, const int* in_sizes, int n_in,
                              void* d_out, int out_size, void* d_ws, size_t ws_size,
                              hipStream_t stream) {
    (void)in_sizes; (void)n_in; (void)out_size; (void)ws_size;
    const float* x      = (const float*)d_in[0];
    const float* logits = (const float*)d_in[1];
    const float* w13    = (const float*)d_in[2];
    const float* w13s   = (const float*)d_in[3];
    const float* w2     = (const float*)d_in[4];
    const float* w2s    = (const float*)d_in[5];
    float* out = (float*)d_out;

    char* ws = (char*)d_ws;
    int*    counts   = (int*)ws;                              // @0
    int*    base     = (int*)(ws + 128);                      // @128
    int*    tok_list = (int*)(ws + 256);                      // 32 KB
    float*  wt_list  = (float*)(ws + 256 + 32768);            // 32 KB
    __bf16* act      = (__bf16*)(ws + 65792);                 // 3 MB
    __bf16* xbf      = (__bf16*)(ws + 65792 + 3145728);       // 2 MB
    __bf16* w13d     = (__bf16*)(ws + 65792 + 3145728 + 2097152);            // 25.2 MB
    __bf16* w2d      = (__bf16*)(ws + 65792 + 3145728 + 2097152 + 25165824); // 12.6 MB

    prep_kernel<<<dim3(10240), 256, 0, stream>>>(w13, w13s, w2, w2s, x,
                                                 (float4*)out, w13d, w2d, xbf);
    router_kernel<<<dim3(1), 1024, 0, stream>>>(logits, counts, base, tok_list, wt_list);
    gemm1_kernel<<<dim3(I_DIM / 64, T_TOK / 32, E_NUM), 256, 0, stream>>>(
        xbf, w13d, counts, base, tok_list, act);
    gemm2_kernel<<<dim3(H_DIM / 128, T_TOK / 32, E_NUM), 256, 0, stream>>>(
        act, w2d, counts, base, tok_list, wt_list, out);
}

// Round 6
// 166.129 us; speedup vs baseline: 1.7712x; 1.7712x over previous
//
#include <hip/hip_runtime.h>

#define T_TOK 1024
#define H_DIM 1024
#define I_DIM 768
#define E_NUM 8

// prep ranges (in 8-element groups)
#define G13 1572864   // 8*1536*1024/8
#define G2   786432   // 8*1024*768/8
#define GX   131072   // 1024*1024/8

typedef __bf16 bf16x8 __attribute__((ext_vector_type(8)));
typedef float  f32x4  __attribute__((ext_vector_type(4)));

__device__ inline bf16x8 cvt8(float4 a, float4 b, float s) {
    bf16x8 o;
    o[0] = (__bf16)(a.x * s); o[1] = (__bf16)(a.y * s);
    o[2] = (__bf16)(a.z * s); o[3] = (__bf16)(a.w * s);
    o[4] = (__bf16)(b.x * s); o[5] = (__bf16)(b.y * s);
    o[6] = (__bf16)(b.z * s); o[7] = (__bf16)(b.w * s);
    return o;
}

// ---- prep: dequant w13/w2 -> bf16, convert x -> bf16, zero out -----------
__global__ __launch_bounds__(256) void prep_kernel(
    const float* __restrict__ w13, const float* __restrict__ w13s,
    const float* __restrict__ w2,  const float* __restrict__ w2s,
    const float* __restrict__ x,   float4* __restrict__ out4,
    __bf16* __restrict__ w13d, __bf16* __restrict__ w2d, __bf16* __restrict__ xbf)
{
    int g = blockIdx.x * 256 + threadIdx.x;
    if (g < G13) {
        int k8 = g & 127;               // 128 groups per 1024-k row
        int row = g >> 7;               // e*1536 + n
        float s = w13s[(row << 3) | (k8 >> 4)];
        const float4* src = (const float4*)w13 + (size_t)g * 2;
        *(bf16x8*)(w13d + (size_t)g * 8) = cvt8(src[0], src[1], s);
    } else if (g < G13 + G2) {
        int g2 = g - G13;
        unsigned row = (unsigned)g2 / 96u;   // e*1024 + h (96 groups per 768-k row)
        int k8 = g2 - row * 96;
        float s = w2s[row * 6 + (k8 >> 4)];
        const float4* src = (const float4*)w2 + (size_t)g2 * 2;
        *(bf16x8*)(w2d + (size_t)g2 * 8) = cvt8(src[0], src[1], s);
    } else if (g < G13 + G2 + GX) {
        int gx = g - (G13 + G2);
        const float4* src = (const float4*)x + (size_t)gx * 2;
        *(bf16x8*)(xbf + (size_t)gx * 8) = cvt8(src[0], src[1], 1.0f);
    } else {
        int go = g - (G13 + G2 + GX);
        float4 z = make_float4(0.f, 0.f, 0.f, 0.f);
        out4[2 * go] = z; out4[2 * go + 1] = z;
    }
}

// ---- router: single block, LDS counters + scan ---------------------------
__global__ __launch_bounds__(1024) void router_kernel(
    const float* __restrict__ logits,
    int* __restrict__ counts, int* __restrict__ base,
    int* __restrict__ tok_list, float* __restrict__ wt_list)
{
    __shared__ int cnt[E_NUM];
    const int t = threadIdx.x;
    if (t < E_NUM) cnt[t] = 0;
    __syncthreads();
    float l[E_NUM];
#pragma unroll
    for (int e = 0; e < E_NUM; e++) l[e] = logits[t * E_NUM + e];
    int e0 = 0; float m0 = l[0];
#pragma unroll
    for (int e = 1; e < E_NUM; e++) if (l[e] > m0) { m0 = l[e]; e0 = e; }
    int e1 = -1; float m1 = -3e38f;
#pragma unroll
    for (int e = 0; e < E_NUM; e++) if (e != e0 && l[e] > m1) { m1 = l[e]; e1 = e; }
    float w0 = 1.0f / (1.0f + expf(m1 - m0));
    float w1 = 1.0f - w0;
    int p0 = atomicAdd(&cnt[e0], 1);
    tok_list[e0 * T_TOK + p0] = t;
    wt_list[e0 * T_TOK + p0] = w0;
    int p1 = atomicAdd(&cnt[e1], 1);
    tok_list[e1 * T_TOK + p1] = t;
    wt_list[e1 * T_TOK + p1] = w1;
    __syncthreads();
    if (t == 0) {
        int s = 0;
        for (int e = 0; e < E_NUM; e++) { base[e] = s; counts[e] = cnt[e]; s += cnt[e]; }
    }
}

#define MFMA(A, B, C) __builtin_amdgcn_mfma_f32_16x16x32_bf16(A, B, C, 0, 0, 0)

// SROA-friendly staging state: named members only, no dynamic indexing.
struct Stage { uint4 a, b0, b1, b2, b3; };

__device__ inline Stage ld_stage(const __bf16* pA, const __bf16* pB, int k) {
    Stage s;
    s.a  = *(const uint4*)(pA + k);
    s.b0 = *(const uint4*)(pB + k);
    s.b1 = *(const uint4*)(pB + k + 8);
    s.b2 = *(const uint4*)(pB + k + 16);
    s.b3 = *(const uint4*)(pB + k + 24);
    return s;
}

__device__ inline void st_stage(char* As, char* Bs, int awo,
                                int bw0, int bw1, int bw2, int bw3,
                                const Stage& s) {
    *(uint4*)(As + awo) = s.a;
    *(uint4*)(Bs + bw0) = s.b0;
    *(uint4*)(Bs + bw1) = s.b1;
    *(uint4*)(Bs + bw2) = s.b2;
    *(uint4*)(Bs + bw3) = s.b3;
}

// ---- GEMM1: gate_up = x_g @ w13d^T, + SiLU -------------------------------
// M=32 x N=128(64 gate+64 up), BK=64, named-register 2-deep pipeline, 1 barrier/step
__global__ __launch_bounds__(256, 4) void gemm1_kernel(
    const __bf16* __restrict__ xbf,
    const __bf16* __restrict__ w13d,
    const int* __restrict__ counts,
    const int* __restrict__ base,
    const int* __restrict__ tok_list,
    __bf16* __restrict__ act)
{
    const int e = blockIdx.z;
    const int count = counts[e];
    const int m0 = blockIdx.y * 32;
    if (m0 >= count) return;
    const int n0 = blockIdx.x * 64;
    const int abase = base[e];

    __shared__ union {
        struct { __bf16 Bs[2][128 * 64]; __bf16 As[2][32 * 64]; } s;  // 40960 B
        float gu[32 * 132];
        int tok[32];
    } u;

    const int tid = threadIdx.x;
    if (tid < 32) {
        int r = m0 + tid;
        u.tok[tid] = (r < count) ? tok_list[e * T_TOK + r] : tok_list[e * T_TOK];
    }
    __syncthreads();
    const int arow = tid >> 3, ag = tid & 7;
    const int tok_a = u.tok[arow];
    __syncthreads();   // tok region aliases Bs[0]; all reads done before staging writes

    const __bf16* pA = xbf + (size_t)tok_a * H_DIM + ag * 8;
    const int awo = arow * 128 + ((ag ^ (arow & 7)) << 4);
    const int brow = tid >> 1, bg0 = (tid & 1) * 4;
    const int nB = (brow < 64) ? (n0 + brow) : (I_DIM + n0 + brow - 64);
    const __bf16* pB = w13d + ((size_t)e * 2 * I_DIM + nB) * H_DIM + bg0 * 8;
    const int bw0 = brow * 128 + (((bg0 + 0) ^ (brow & 7)) << 4);
    const int bw1 = brow * 128 + (((bg0 + 1) ^ (brow & 7)) << 4);
    const int bw2 = brow * 128 + (((bg0 + 2) ^ (brow & 7)) << 4);
    const int bw3 = brow * 128 + (((bg0 + 3) ^ (brow & 7)) << 4);

    const int wid = tid >> 6, lane = tid & 63, lrow = lane & 15, quad = lane >> 4;
    int aoff[2][2], boff[2][2];
#pragma unroll
    for (int kk = 0; kk < 2; kk++) {
        int gph = ((kk * 4 + quad) ^ (lrow & 7)) << 4;
#pragma unroll
        for (int i = 0; i < 2; i++) {
            aoff[kk][i] = (i * 16 + lrow) * 128 + gph;
            boff[kk][i] = (wid * 32 + i * 16 + lrow) * 128 + gph;
        }
    }

    f32x4 acc[2][2];
#pragma unroll
    for (int i = 0; i < 2; i++)
#pragma unroll
        for (int j = 0; j < 2; j++) { f32x4 z = {0.f, 0.f, 0.f, 0.f}; acc[i][j] = z; }

    char* A0 = (char*)u.s.As[0]; char* A1 = (char*)u.s.As[1];
    char* B0 = (char*)u.s.Bs[0]; char* B1 = (char*)u.s.Bs[1];

    auto compute = [&](const char* Ab, const char* Bb) {
#pragma unroll
        for (int kk = 0; kk < 2; kk++) {
            bf16x8 a0 = *(const bf16x8*)(Ab + aoff[kk][0]);
            bf16x8 a1 = *(const bf16x8*)(Ab + aoff[kk][1]);
            bf16x8 b0 = *(const bf16x8*)(Bb + boff[kk][0]);
            bf16x8 b1 = *(const bf16x8*)(Bb + boff[kk][1]);
            acc[0][0] = MFMA(a0, b0, acc[0][0]);
            acc[1][0] = MFMA(a1, b0, acc[1][0]);
            acc[0][1] = MFMA(a0, b1, acc[0][1]);
            acc[1][1] = MFMA(a1, b1, acc[1][1]);
        }
    };

    // pipeline: contents 0..15 (K = 16*64)
    Stage X = ld_stage(pA, pB, 0);
    Stage Y = ld_stage(pA, pB, 64);
    st_stage(A0, B0, awo, bw0, bw1, bw2, bw3, X);   // buf0 <- c0
    X = ld_stage(pA, pB, 2 * 64);                   // X <- c2
    __syncthreads();

#pragma unroll
    for (int uu = 0; uu < 8; ++uu) {
        // stepA: buf0 has c(2u); write buf1 <- Y=c(2u+1); Y <- L(2u+3)
        st_stage(A1, B1, awo, bw0, bw1, bw2, bw3, Y);
        if (2 * uu + 3 < 16) Y = ld_stage(pA, pB, (2 * uu + 3) * 64);
        compute(A0, B0);
        __syncthreads();
        // stepB: buf1 has c(2u+1); write buf0 <- X=c(2u+2); X <- L(2u+4)
        if (uu < 7) st_stage(A0, B0, awo, bw0, bw1, bw2, bw3, X);
        if (2 * uu + 4 < 16) X = ld_stage(pA, pB, (2 * uu + 4) * 64);
        compute(A1, B1);
        __syncthreads();
    }

    // epilogue: staging dead; reuse union as gu
#pragma unroll
    for (int i = 0; i < 2; i++)
#pragma unroll
        for (int j = 0; j < 2; j++)
#pragma unroll
            for (int r = 0; r < 4; r++) {
                int m = i * 16 + quad * 4 + r;
                int c = wid * 32 + j * 16 + lrow;
                u.gu[m * 132 + c] = acc[i][j][r];
            }
    __syncthreads();

#pragma unroll
    for (int ii = 0; ii < 8; ii++) {
        int o = ii * 256 + tid;
        int m = o >> 6, c = o & 63;
        if (m0 + m < count) {
            float g  = u.gu[m * 132 + c];
            float up = u.gu[m * 132 + 64 + c];
            float a  = g / (1.0f + expf(-g)) * up;
            act[(size_t)(abase + m0 + m) * I_DIM + n0 + c] = (__bf16)a;
        }
    }
}

// ---- GEMM2: out += w * (act @ w2d^T) -------------------------------------
// M=32 x N=128, BK=64, named-register 2-deep pipeline, 1 barrier/step
__global__ __launch_bounds__(256, 4) void gemm2_kernel(
    const __bf16* __restrict__ act,
    const __bf16* __restrict__ w2d,
    const int* __restrict__ counts,
    const int* __restrict__ base,
    const int* __restrict__ tok_list,
    const float* __restrict__ wt_list,
    float* __restrict__ out)
{
    const int e = blockIdx.z;
    const int count = counts[e];
    const int m0 = blockIdx.y * 32;
    if (m0 >= count) return;
    const int n0 = blockIdx.x * 128;
    const int abase = base[e];

    __shared__ struct { __bf16 Bs[2][128 * 64]; __bf16 As[2][32 * 64]; } s;  // 40960 B

    const int tid = threadIdx.x;
    const int arow = tid >> 3, ag = tid & 7;
    int gr = abase + m0 + arow;
    if (gr > 2 * T_TOK - 1) gr = 2 * T_TOK - 1;
    const __bf16* pA = act + (size_t)gr * I_DIM + ag * 8;
    const int awo = arow * 128 + ((ag ^ (arow & 7)) << 4);

    const int brow = tid >> 1, bg0 = (tid & 1) * 4;
    const __bf16* pB = w2d + ((size_t)e * H_DIM + n0 + brow) * I_DIM + bg0 * 8;
    const int bw0 = brow * 128 + (((bg0 + 0) ^ (brow & 7)) << 4);
    const int bw1 = brow * 128 + (((bg0 + 1) ^ (brow & 7)) << 4);
    const int bw2 = brow * 128 + (((bg0 + 2) ^ (brow & 7)) << 4);
    const int bw3 = brow * 128 + (((bg0 + 3) ^ (brow & 7)) << 4);

    const int wid = tid >> 6, lane = tid & 63, lrow = lane & 15, quad = lane >> 4;
    int aoff[2][2], boff[2][2];
#pragma unroll
    for (int kk = 0; kk < 2; kk++) {
        int gph = ((kk * 4 + quad) ^ (lrow & 7)) << 4;
#pragma unroll
        for (int i = 0; i < 2; i++) {
            aoff[kk][i] = (i * 16 + lrow) * 128 + gph;
            boff[kk][i] = (wid * 32 + i * 16 + lrow) * 128 + gph;
        }
    }

    f32x4 acc[2][2];
#pragma unroll
    for (int i = 0; i < 2; i++)
#pragma unroll
        for (int j = 0; j < 2; j++) { f32x4 z = {0.f, 0.f, 0.f, 0.f}; acc[i][j] = z; }

    char* A0 = (char*)s.As[0]; char* A1 = (char*)s.As[1];
    char* B0 = (char*)s.Bs[0]; char* B1 = (char*)s.Bs[1];

    auto compute = [&](const char* Ab, const char* Bb) {
#pragma unroll
        for (int kk = 0; kk < 2; kk++) {
            bf16x8 a0 = *(const bf16x8*)(Ab + aoff[kk][0]);
            bf16x8 a1 = *(const bf16x8*)(Ab + aoff[kk][1]);
            bf16x8 b0 = *(const bf16x8*)(Bb + boff[kk][0]);
            bf16x8 b1 = *(const bf16x8*)(Bb + boff[kk][1]);
            acc[0][0] = MFMA(a0, b0, acc[0][0]);
            acc[1][0] = MFMA(a1, b0, acc[1][0]);
            acc[0][1] = MFMA(a0, b1, acc[0][1]);
            acc[1][1] = MFMA(a1, b1, acc[1][1]);
        }
    };

    // pipeline: contents 0..11 (K = 12*64 = 768)
    Stage X = ld_stage(pA, pB, 0);
    Stage Y = ld_stage(pA, pB, 64);
    st_stage(A0, B0, awo, bw0, bw1, bw2, bw3, X);   // buf0 <- c0
    X = ld_stage(pA, pB, 2 * 64);                   // X <- c2
    __syncthreads();

#pragma unroll
    for (int uu = 0; uu < 6; ++uu) {
        st_stage(A1, B1, awo, bw0, bw1, bw2, bw3, Y);
        if (2 * uu + 3 < 12) Y = ld_stage(pA, pB, (2 * uu + 3) * 64);
        compute(A0, B0);
        __syncthreads();
        if (uu < 5) st_stage(A0, B0, awo, bw0, bw1, bw2, bw3, X);
        if (2 * uu + 4 < 12) X = ld_stage(pA, pB, (2 * uu + 4) * 64);
        compute(A1, B1);
        __syncthreads();
    }

    // weighted atomic scatter (tok/wt via broadcast-coalesced global loads)
#pragma unroll
    for (int i = 0; i < 2; i++)
#pragma unroll
        for (int r = 0; r < 4; r++) {
            int m = i * 16 + quad * 4 + r;
            if (m0 + m < count) {
                int   t = tok_list[e * T_TOK + m0 + m];
                float w = wt_list[e * T_TOK + m0 + m];
#pragma unroll
                for (int j = 0; j < 2; j++) {
                    int h = n0 + wid * 32 + j * 16 + lrow;
                    atomicAdd(&out[(size_t)t * H_DIM + h], w * acc[i][j][r]);
                }
            }
        }
}

extern "C" void kernel_launch(void* const* d_in, const int* in_sizes, int n_in,
                              void* d_out, int out_size, void* d_ws, size_t ws_size,
                              hipStream_t stream) {
    (void)in_sizes; (void)n_in; (void)out_size; (void)ws_size;
    const float* x      = (const float*)d_in[0];
    const float* logits = (const float*)d_in[1];
    const float* w13    = (const float*)d_in[2];
    const float* w13s   = (const float*)d_in[3];
    const float* w2     = (const float*)d_in[4];
    const float* w2s    = (const float*)d_in[5];
    float* out = (float*)d_out;

    char* ws = (char*)d_ws;
    int*    counts   = (int*)ws;                              // @0
    int*    base     = (int*)(ws + 128);                      // @128
    int*    tok_list = (int*)(ws + 256);                      // 32 KB
    float*  wt_list  = (float*)(ws + 256 + 32768);            // 32 KB
    __bf16* act      = (__bf16*)(ws + 65792);                 // 3 MB
    __bf16* xbf      = (__bf16*)(ws + 65792 + 3145728);       // 2 MB
    __bf16* w13d     = (__bf16*)(ws + 65792 + 3145728 + 2097152);            // 25.2 MB
    __bf16* w2d      = (__bf16*)(ws + 65792 + 3145728 + 2097152 + 25165824); // 12.6 MB

    prep_kernel<<<dim3(10240), 256, 0, stream>>>(w13, w13s, w2, w2s, x,
                                                 (float4*)out, w13d, w2d, xbf);
    router_kernel<<<dim3(1), 1024, 0, stream>>>(logits, counts, base, tok_list, wt_list);
    gemm1_kernel<<<dim3(I_DIM / 64, T_TOK / 32, E_NUM), 256, 0, stream>>>(
        xbf, w13d, counts, base, tok_list, act);
    gemm2_kernel<<<dim3(H_DIM / 128, T_TOK / 32, E_NUM), 256, 0, stream>>>(
        act, w2d, counts, base, tok_list, wt_list, out);
}

// Round 7
// 154.054 us; speedup vs baseline: 1.9100x; 1.0784x over previous
//
#include <hip/hip_runtime.h>

#define T_TOK 1024
#define H_DIM 1024
#define I_DIM 768
#define E_NUM 8

// prep ranges (in 8-element groups)
#define G13 1572864   // 8*1536*1024/8
#define G2   786432   // 8*1024*768/8
#define GX   131072   // 1024*1024/8

typedef __bf16 bf16x8 __attribute__((ext_vector_type(8)));
typedef float  f32x4  __attribute__((ext_vector_type(4)));

__device__ inline bf16x8 cvt8(float4 a, float4 b, float s) {
    bf16x8 o;
    o[0] = (__bf16)(a.x * s); o[1] = (__bf16)(a.y * s);
    o[2] = (__bf16)(a.z * s); o[3] = (__bf16)(a.w * s);
    o[4] = (__bf16)(b.x * s); o[5] = (__bf16)(b.y * s);
    o[6] = (__bf16)(b.z * s); o[7] = (__bf16)(b.w * s);
    return o;
}

// ---- prep: dequant w13/w2 -> bf16, convert x -> bf16, zero out -----------
__global__ __launch_bounds__(256) void prep_kernel(
    const float* __restrict__ w13, const float* __restrict__ w13s,
    const float* __restrict__ w2,  const float* __restrict__ w2s,
    const float* __restrict__ x,   float4* __restrict__ out4,
    __bf16* __restrict__ w13d, __bf16* __restrict__ w2d, __bf16* __restrict__ xbf)
{
    int g = blockIdx.x * 256 + threadIdx.x;
    if (g < G13) {
        int k8 = g & 127;               // 128 groups per 1024-k row
        int row = g >> 7;               // e*1536 + n
        float s = w13s[(row << 3) | (k8 >> 4)];
        const float4* src = (const float4*)w13 + (size_t)g * 2;
        *(bf16x8*)(w13d + (size_t)g * 8) = cvt8(src[0], src[1], s);
    } else if (g < G13 + G2) {
        int g2 = g - G13;
        unsigned row = (unsigned)g2 / 96u;   // e*1024 + h (96 groups per 768-k row)
        int k8 = g2 - row * 96;
        float s = w2s[row * 6 + (k8 >> 4)];
        const float4* src = (const float4*)w2 + (size_t)g2 * 2;
        *(bf16x8*)(w2d + (size_t)g2 * 8) = cvt8(src[0], src[1], s);
    } else if (g < G13 + G2 + GX) {
        int gx = g - (G13 + G2);
        const float4* src = (const float4*)x + (size_t)gx * 2;
        *(bf16x8*)(xbf + (size_t)gx * 8) = cvt8(src[0], src[1], 1.0f);
    } else {
        int go = g - (G13 + G2 + GX);
        float4 z = make_float4(0.f, 0.f, 0.f, 0.f);
        out4[2 * go] = z; out4[2 * go + 1] = z;
    }
}

// ---- router: single block, LDS counters + scan ---------------------------
__global__ __launch_bounds__(1024) void router_kernel(
    const float* __restrict__ logits,
    int* __restrict__ counts, int* __restrict__ base,
    int* __restrict__ tok_list, float* __restrict__ wt_list)
{
    __shared__ int cnt[E_NUM];
    const int t = threadIdx.x;
    if (t < E_NUM) cnt[t] = 0;
    __syncthreads();
    float l[E_NUM];
#pragma unroll
    for (int e = 0; e < E_NUM; e++) l[e] = logits[t * E_NUM + e];
    int e0 = 0; float m0 = l[0];
#pragma unroll
    for (int e = 1; e < E_NUM; e++) if (l[e] > m0) { m0 = l[e]; e0 = e; }
    int e1 = -1; float m1 = -3e38f;
#pragma unroll
    for (int e = 0; e < E_NUM; e++) if (e != e0 && l[e] > m1) { m1 = l[e]; e1 = e; }
    float w0 = 1.0f / (1.0f + expf(m1 - m0));
    float w1 = 1.0f - w0;
    int p0 = atomicAdd(&cnt[e0], 1);
    tok_list[e0 * T_TOK + p0] = t;
    wt_list[e0 * T_TOK + p0] = w0;
    int p1 = atomicAdd(&cnt[e1], 1);
    tok_list[e1 * T_TOK + p1] = t;
    wt_list[e1 * T_TOK + p1] = w1;
    __syncthreads();
    if (t == 0) {
        int s = 0;
        for (int e = 0; e < E_NUM; e++) { base[e] = s; counts[e] = cnt[e]; s += cnt[e]; }
    }
}

#define MFMA(A, B, C) __builtin_amdgcn_mfma_f32_16x16x32_bf16(A, B, C, 0, 0, 0)

// SROA-friendly staging state: named members only, no dynamic indexing.
struct Stage { uint4 a0, a1, b0, b1, b2, b3; };

__device__ inline Stage ld_stage(const __bf16* pA0, const __bf16* pA1,
                                 const __bf16* pB, int k) {
    Stage s;
    s.a0 = *(const uint4*)(pA0 + k);
    s.a1 = *(const uint4*)(pA1 + k);
    s.b0 = *(const uint4*)(pB + k);
    s.b1 = *(const uint4*)(pB + k + 8);
    s.b2 = *(const uint4*)(pB + k + 16);
    s.b3 = *(const uint4*)(pB + k + 24);
    return s;
}

__device__ inline void st_stage(char* As, char* Bs, int aw0, int aw1,
                                int bw0, int bw1, int bw2, int bw3,
                                const Stage& s) {
    *(uint4*)(As + aw0) = s.a0;
    *(uint4*)(As + aw1) = s.a1;
    *(uint4*)(Bs + bw0) = s.b0;
    *(uint4*)(Bs + bw1) = s.b1;
    *(uint4*)(Bs + bw2) = s.b2;
    *(uint4*)(Bs + bw3) = s.b3;
}

// ---- GEMM1: gate_up = x_g @ w13d^T, + SiLU -------------------------------
// M=64 x N=128(64 gate+64 up), BK=64, XCD-swizzled 1-D grid, reg pipeline
__global__ __launch_bounds__(256, 3) void gemm1_kernel(
    const __bf16* __restrict__ xbf,
    const __bf16* __restrict__ w13d,
    const int* __restrict__ counts,
    const int* __restrict__ base,
    const int* __restrict__ tok_list,
    __bf16* __restrict__ act)
{
    // XCD-aware decode: xcd = bx&7; within an XCD, m varies slowest so the
    // ~3 MB per-XCD B working set stays L2-resident across m rounds.
    const int bx = blockIdx.x;
    const int xcd = bx & 7, t = bx >> 3;
    const int p = t % 12, m = t / 12;      // 12 pairs per XCD, 16 m rounds
    const int P = xcd + 8 * p;             // pair id in [0,96)
    const int nb = P % 12, e = P / 12;
    const int count = counts[e];
    const int m0 = m * 64;
    if (m0 >= count) return;
    const int n0 = nb * 64;
    const int abase = base[e];

    __shared__ union {
        struct { __bf16 Bs[2][128 * 64]; __bf16 As[2][64 * 64]; } s;  // 49152 B
        float gu[64 * 132];                                           // 33792 B
    } u;
    __shared__ int tokS[64];

    const int tid = threadIdx.x;
    if (tid < 64) {
        int r = m0 + tid;
        tokS[tid] = (r < count) ? tok_list[e * T_TOK + r] : tok_list[e * T_TOK];
    }
    __syncthreads();

    // A staging: rows arow and arow+32, granule ag (16B granules, XOR swizzle)
    const int arow = tid >> 3, ag = tid & 7;
    const __bf16* pA0 = xbf + (size_t)tokS[arow] * H_DIM + ag * 8;
    const __bf16* pA1 = xbf + (size_t)tokS[arow + 32] * H_DIM + ag * 8;
    const int aw0 = arow * 128 + ((ag ^ (arow & 7)) << 4);
    const int aw1 = aw0 + 32 * 128;
    // B staging: 4 granules per thread on row brow
    const int brow = tid >> 1, bg0 = (tid & 1) * 4;
    const int nB = (brow < 64) ? (n0 + brow) : (I_DIM + n0 + brow - 64);
    const __bf16* pB = w13d + ((size_t)e * 2 * I_DIM + nB) * H_DIM + bg0 * 8;
    const int bw0 = brow * 128 + (((bg0 + 0) ^ (brow & 7)) << 4);
    const int bw1 = brow * 128 + (((bg0 + 1) ^ (brow & 7)) << 4);
    const int bw2 = brow * 128 + (((bg0 + 2) ^ (brow & 7)) << 4);
    const int bw3 = brow * 128 + (((bg0 + 3) ^ (brow & 7)) << 4);

    const int wid = tid >> 6, lane = tid & 63, lrow = lane & 15, quad = lane >> 4;
    int aoff[2][4], boff[2][2];
#pragma unroll
    for (int kk = 0; kk < 2; kk++) {
        int gph = ((kk * 4 + quad) ^ (lrow & 7)) << 4;
#pragma unroll
        for (int i = 0; i < 4; i++) aoff[kk][i] = (i * 16 + lrow) * 128 + gph;
#pragma unroll
        for (int j = 0; j < 2; j++) boff[kk][j] = (wid * 32 + j * 16 + lrow) * 128 + gph;
    }

    f32x4 acc[4][2];
#pragma unroll
    for (int i = 0; i < 4; i++)
#pragma unroll
        for (int j = 0; j < 2; j++) { f32x4 z = {0.f, 0.f, 0.f, 0.f}; acc[i][j] = z; }

    char* A0 = (char*)u.s.As[0]; char* A1 = (char*)u.s.As[1];
    char* B0 = (char*)u.s.Bs[0]; char* B1 = (char*)u.s.Bs[1];

    auto compute = [&](const char* Ab, const char* Bb) {
#pragma unroll
        for (int kk = 0; kk < 2; kk++) {
            bf16x8 b0 = *(const bf16x8*)(Bb + boff[kk][0]);
            bf16x8 b1 = *(const bf16x8*)(Bb + boff[kk][1]);
#pragma unroll
            for (int i = 0; i < 4; i++) {
                bf16x8 a = *(const bf16x8*)(Ab + aoff[kk][i]);
                acc[i][0] = MFMA(a, b0, acc[i][0]);
                acc[i][1] = MFMA(a, b1, acc[i][1]);
            }
        }
    };

    // pipeline: contents 0..15 (K = 16*64)
    Stage X = ld_stage(pA0, pA1, pB, 0);
    Stage Y = ld_stage(pA0, pA1, pB, 64);
    st_stage(A0, B0, aw0, aw1, bw0, bw1, bw2, bw3, X);
    X = ld_stage(pA0, pA1, pB, 2 * 64);
    __syncthreads();

#pragma unroll
    for (int uu = 0; uu < 8; ++uu) {
        st_stage(A1, B1, aw0, aw1, bw0, bw1, bw2, bw3, Y);
        if (2 * uu + 3 < 16) Y = ld_stage(pA0, pA1, pB, (2 * uu + 3) * 64);
        compute(A0, B0);
        __syncthreads();
        if (uu < 7) st_stage(A0, B0, aw0, aw1, bw0, bw1, bw2, bw3, X);
        if (2 * uu + 4 < 16) X = ld_stage(pA0, pA1, pB, (2 * uu + 4) * 64);
        compute(A1, B1);
        __syncthreads();
    }

    // epilogue: staging dead; reuse union as gu
#pragma unroll
    for (int i = 0; i < 4; i++)
#pragma unroll
        for (int j = 0; j < 2; j++)
#pragma unroll
            for (int r = 0; r < 4; r++) {
                int mr = i * 16 + quad * 4 + r;
                int c = wid * 32 + j * 16 + lrow;
                u.gu[mr * 132 + c] = acc[i][j][r];
            }
    __syncthreads();

#pragma unroll
    for (int ii = 0; ii < 16; ii++) {
        int o = ii * 256 + tid;
        int mr = o >> 6, c = o & 63;
        if (m0 + mr < count) {
            float g  = u.gu[mr * 132 + c];
            float up = u.gu[mr * 132 + 64 + c];
            float a  = g / (1.0f + expf(-g)) * up;
            act[(size_t)(abase + m0 + mr) * I_DIM + n0 + c] = (__bf16)a;
        }
    }
}

// ---- GEMM2: out += w * (act @ w2d^T) -------------------------------------
// M=64 x N=128, BK=64, XCD-swizzled 1-D grid (n fixed per XCD), reg pipeline
__global__ __launch_bounds__(256, 3) void gemm2_kernel(
    const __bf16* __restrict__ act,
    const __bf16* __restrict__ w2d,
    const int* __restrict__ counts,
    const int* __restrict__ base,
    const int* __restrict__ tok_list,
    const float* __restrict__ wt_list,
    float* __restrict__ out)
{
    const int bx = blockIdx.x;
    const int xcd = bx & 7, t = bx >> 3;
    const int p = t & 7, m = t >> 3;       // 8 pairs per XCD, 16 m rounds
    const int P = xcd + 8 * p;             // pair id in [0,64)
    const int nb = P & 7, e = P >> 3;      // => nb == xcd: n-slice pinned per XCD
    const int count = counts[e];
    const int m0 = m * 64;
    if (m0 >= count) return;
    const int n0 = nb * 128;
    const int abase = base[e];

    __shared__ struct { __bf16 Bs[2][128 * 64]; __bf16 As[2][64 * 64]; } s;  // 49152 B

    const int tid = threadIdx.x;
    const int arow = tid >> 3, ag = tid & 7;
    int gr0 = abase + m0 + arow;      if (gr0 > 2 * T_TOK - 1) gr0 = 2 * T_TOK - 1;
    int gr1 = abase + m0 + arow + 32; if (gr1 > 2 * T_TOK - 1) gr1 = 2 * T_TOK - 1;
    const __bf16* pA0 = act + (size_t)gr0 * I_DIM + ag * 8;
    const __bf16* pA1 = act + (size_t)gr1 * I_DIM + ag * 8;
    const int aw0 = arow * 128 + ((ag ^ (arow & 7)) << 4);
    const int aw1 = aw0 + 32 * 128;

    const int brow = tid >> 1, bg0 = (tid & 1) * 4;
    const __bf16* pB = w2d + ((size_t)e * H_DIM + n0 + brow) * I_DIM + bg0 * 8;
    const int bw0 = brow * 128 + (((bg0 + 0) ^ (brow & 7)) << 4);
    const int bw1 = brow * 128 + (((bg0 + 1) ^ (brow & 7)) << 4);
    const int bw2 = brow * 128 + (((bg0 + 2) ^ (brow & 7)) << 4);
    const int bw3 = brow * 128 + (((bg0 + 3) ^ (brow & 7)) << 4);

    const int wid = tid >> 6, lane = tid & 63, lrow = lane & 15, quad = lane >> 4;
    int aoff[2][4], boff[2][2];
#pragma unroll
    for (int kk = 0; kk < 2; kk++) {
        int gph = ((kk * 4 + quad) ^ (lrow & 7)) << 4;
#pragma unroll
        for (int i = 0; i < 4; i++) aoff[kk][i] = (i * 16 + lrow) * 128 + gph;
#pragma unroll
        for (int j = 0; j < 2; j++) boff[kk][j] = (wid * 32 + j * 16 + lrow) * 128 + gph;
    }

    f32x4 acc[4][2];
#pragma unroll
    for (int i = 0; i < 4; i++)
#pragma unroll
        for (int j = 0; j < 2; j++) { f32x4 z = {0.f, 0.f, 0.f, 0.f}; acc[i][j] = z; }

    char* A0 = (char*)s.As[0]; char* A1 = (char*)s.As[1];
    char* B0 = (char*)s.Bs[0]; char* B1 = (char*)s.Bs[1];

    auto compute = [&](const char* Ab, const char* Bb) {
#pragma unroll
        for (int kk = 0; kk < 2; kk++) {
            bf16x8 b0 = *(const bf16x8*)(Bb + boff[kk][0]);
            bf16x8 b1 = *(const bf16x8*)(Bb + boff[kk][1]);
#pragma unroll
            for (int i = 0; i < 4; i++) {
                bf16x8 a = *(const bf16x8*)(Ab + aoff[kk][i]);
                acc[i][0] = MFMA(a, b0, acc[i][0]);
                acc[i][1] = MFMA(a, b1, acc[i][1]);
            }
        }
    };

    // pipeline: contents 0..11 (K = 12*64 = 768)
    Stage X = ld_stage(pA0, pA1, pB, 0);
    Stage Y = ld_stage(pA0, pA1, pB, 64);
    st_stage(A0, B0, aw0, aw1, bw0, bw1, bw2, bw3, X);
    X = ld_stage(pA0, pA1, pB, 2 * 64);
    __syncthreads();

#pragma unroll
    for (int uu = 0; uu < 6; ++uu) {
        st_stage(A1, B1, aw0, aw1, bw0, bw1, bw2, bw3, Y);
        if (2 * uu + 3 < 12) Y = ld_stage(pA0, pA1, pB, (2 * uu + 3) * 64);
        compute(A0, B0);
        __syncthreads();
        if (uu < 5) st_stage(A0, B0, aw0, aw1, bw0, bw1, bw2, bw3, X);
        if (2 * uu + 4 < 12) X = ld_stage(pA0, pA1, pB, (2 * uu + 4) * 64);
        compute(A1, B1);
        __syncthreads();
    }

    // weighted atomic scatter (tok/wt via broadcast-coalesced global loads)
#pragma unroll
    for (int i = 0; i < 4; i++)
#pragma unroll
        for (int r = 0; r < 4; r++) {
            int mr = i * 16 + quad * 4 + r;
            if (m0 + mr < count) {
                int   tk = tok_list[e * T_TOK + m0 + mr];
                float w  = wt_list[e * T_TOK + m0 + mr];
#pragma unroll
                for (int j = 0; j < 2; j++) {
                    int h = n0 + wid * 32 + j * 16 + lrow;
                    atomicAdd(&out[(size_t)tk * H_DIM + h], w * acc[i][j][r]);
                }
            }
        }
}

extern "C" void kernel_launch(void* const* d_in, const int* in_sizes, int n_in,
                              void* d_out, int out_size, void* d_ws, size_t ws_size,
                              hipStream_t stream) {
    (void)in_sizes; (void)n_in; (void)out_size; (void)ws_size;
    const float* x      = (const float*)d_in[0];
    const float* logits = (const float*)d_in[1];
    const float* w13    = (const float*)d_in[2];
    const float* w13s   = (const float*)d_in[3];
    const float* w2     = (const float*)d_in[4];
    const float* w2s    = (const float*)d_in[5];
    float* out = (float*)d_out;

    char* ws = (char*)d_ws;
    int*    counts   = (int*)ws;                              // @0
    int*    base     = (int*)(ws + 128);                      // @128
    int*    tok_list = (int*)(ws + 256);                      // 32 KB
    float*  wt_list  = (float*)(ws + 256 + 32768);            // 32 KB
    __bf16* act      = (__bf16*)(ws + 65792);                 // 3 MB
    __bf16* xbf      = (__bf16*)(ws + 65792 + 3145728);       // 2 MB
    __bf16* w13d     = (__bf16*)(ws + 65792 + 3145728 + 2097152);            // 25.2 MB
    __bf16* w2d      = (__bf16*)(ws + 65792 + 3145728 + 2097152 + 25165824); // 12.6 MB

    prep_kernel<<<dim3(10240), 256, 0, stream>>>(w13, w13s, w2, w2s, x,
                                                 (float4*)out, w13d, w2d, xbf);
    router_kernel<<<dim3(1), 1024, 0, stream>>>(logits, counts, base, tok_list, wt_list);
    gemm1_kernel<<<dim3(1536), 256, 0, stream>>>(
        xbf, w13d, counts, base, tok_list, act);
    gemm2_kernel<<<dim3(1024), 256, 0, stream>>>(
        act, w2d, counts, base, tok_list, wt_list, out);
}